// Round 3
// baseline (533.530 us; speedup 1.0000x reference)
//
#include <hip/hip_runtime.h>
#include <math.h>

#define N_   8192
#define IN_  512
#define ZD   128
#define CC   64
#define HD   50
#define EPSF 1e-8f

typedef float vf4 __attribute__((ext_vector_type(4)));

__device__ __forceinline__ float softplus_f(float t) {
    return fmaxf(t, 0.f) + log1pf(expf(-fabsf(t)));   // stable softplus
}

// ============================================================================
// k_pre: fused preprocessing.
//   blocks 0..63    : per-category grouping (LDS histogram -> own index list)
//   blocks 64..191  : W1 transpose (pad cols 50->64 with zeros)
//   blocks 192..447 : fz = z @ Wz + bz   (register-tiled 4x4)
// ============================================================================
__global__ __launch_bounds__(256) void k_pre(const int* __restrict__ c,
                                             const float* __restrict__ W1,
                                             const float* __restrict__ z,
                                             const float* __restrict__ Wz,
                                             const float* __restrict__ bz,
                                             float* __restrict__ W1t,
                                             float* __restrict__ fz,
                                             int* __restrict__ counts,
                                             int* __restrict__ offsets,
                                             int* __restrict__ grouped) {
    int tid = threadIdx.x;
    int b   = blockIdx.x;
    if (b < CC) {
        // ---- grouping for category b: no cross-block atomics ----
        __shared__ int hist[CC];
        __shared__ int cursor;
        __shared__ int off_s;
        if (tid < CC) hist[tid] = 0;
        if (tid == 0) cursor = 0;
        __syncthreads();
        for (int i = tid; i < N_; i += 256) atomicAdd(&hist[c[i]], 1);
        __syncthreads();
        if (tid == 0) {
            int off = 0;
            for (int q = 0; q < b; ++q) off += hist[q];
            off_s = off;
            counts[b]  = hist[b];
            offsets[b] = off;
        }
        __syncthreads();
        int off = off_s;
        for (int i = tid; i < N_; i += 256) {
            if (c[i] == b) {
                int p = atomicAdd(&cursor, 1);
                grouped[off + p] = i;
            }
        }
    } else if (b < 192) {
        // ---- W1t[k][d] = W1[d][k], k padded to 64 ----
        int idx = (b - 64) * 256 + tid;          // 64*512 = 32768
        int k = idx >> 9, d = idx & 511;
        W1t[idx] = (k < HD) ? W1[d * HD + k] : 0.f;
    } else {
        // ---- fz = z @ Wz + bz: 32 rows/block, thread = 4 rows x 4 cols ----
        __shared__ float sz[32 * ZD];            // 16 KB
        int row0 = (b - 192) * 32;
        vf4* s4 = (vf4*)sz;
        const vf4* z4 = (const vf4*)(z + (size_t)row0 * ZD);
        #pragma unroll
        for (int f = 0; f < 4; ++f) s4[tid + f * 256] = z4[tid + f * 256];
        __syncthreads();
        int cp = tid & 31, rg = tid >> 5;        // cols 4cp.., rows rg*4..
        const vf4* Wz4 = (const vf4*)Wz;
        vf4 bb = ((const vf4*)bz)[cp];
        vf4 acc[4];
        #pragma unroll
        for (int r = 0; r < 4; ++r) acc[r] = bb;
        for (int d4 = 0; d4 < 32; ++d4) {
            vf4 w0 = Wz4[(4 * d4 + 0) * 32 + cp];
            vf4 w1 = Wz4[(4 * d4 + 1) * 32 + cp];
            vf4 w2 = Wz4[(4 * d4 + 2) * 32 + cp];
            vf4 w3 = Wz4[(4 * d4 + 3) * 32 + cp];
            #pragma unroll
            for (int r = 0; r < 4; ++r) {
                vf4 a = s4[(rg * 4 + r) * 32 + d4];
                acc[r] += a[0] * w0;
                acc[r] += a[1] * w1;
                acc[r] += a[2] * w2;
                acc[r] += a[3] * w3;
            }
        }
        vf4* fz4 = (vf4*)fz;
        #pragma unroll
        for (int r = 0; r < 4; ++r)
            fz4[(size_t)(row0 + rg * 4 + r) * 32 + cp] = acc[r];
    }
}

// ============================================================================
// k_hfx: h = relu(x@W1+b1) computed into LDS, then fx = h@W2+b2 from LDS.
//   32 rows/block, 256 blocks. LDS: 64KB x-tile + 8KB h-tile.
// ============================================================================
__global__ __launch_bounds__(256) void k_hfx(const float* __restrict__ x,
                                             const float* __restrict__ W1t,
                                             const float* __restrict__ b1,
                                             const float* __restrict__ W2,
                                             const float* __restrict__ b2,
                                             float* __restrict__ fx) {
    __shared__ float sx[32 * IN_];               // 64 KB
    __shared__ float sh[32 * 64];                // 8 KB
    int tid  = threadIdx.x;
    int row0 = blockIdx.x * 32;
    vf4* sx4 = (vf4*)sx;
    const vf4* x4 = (const vf4*)(x + (size_t)row0 * IN_);
    #pragma unroll
    for (int f = 0; f < 16; ++f) sx4[tid + f * 256] = x4[tid + f * 256];
    __syncthreads();

    // ---- phase 1: h-tile (32 x 64). thread = 2 rows x 4 cols ----
    {
        int cp = tid & 15, rg = tid >> 4;        // cols 4cp.., rows rg*2..
        const vf4* W1t4 = (const vf4*)W1t;
        vf4 acc0 = {0.f, 0.f, 0.f, 0.f}, acc1 = {0.f, 0.f, 0.f, 0.f};
        for (int d4 = 0; d4 < 128; ++d4) {
            vf4 a0 = sx4[(rg * 2 + 0) * 128 + d4];
            vf4 a1 = sx4[(rg * 2 + 1) * 128 + d4];
            #pragma unroll
            for (int i = 0; i < 4; ++i) {
                vf4 w = W1t4[(4 * cp + i) * 128 + d4];
                acc0[i] += a0[0] * w[0] + a0[1] * w[1] + a0[2] * w[2] + a0[3] * w[3];
                acc1[i] += a1[0] * w[0] + a1[1] * w[1] + a1[2] * w[2] + a1[3] * w[3];
            }
        }
        vf4 bb;
        #pragma unroll
        for (int i = 0; i < 4; ++i) {
            int k = 4 * cp + i;
            bb[i] = (k < HD) ? b1[k] : 0.f;
        }
        vf4* sh4 = (vf4*)sh;
        vf4 h0, h1;
        #pragma unroll
        for (int i = 0; i < 4; ++i) {
            h0[i] = fmaxf(acc0[i] + bb[i], 0.f);
            h1[i] = fmaxf(acc1[i] + bb[i], 0.f);
        }
        sh4[(rg * 2 + 0) * 16 + cp] = h0;
        sh4[(rg * 2 + 1) * 16 + cp] = h1;
    }
    __syncthreads();

    // ---- phase 2: fx-tile (32 x 128). thread = 4 rows x 4 cols ----
    {
        int cp = tid & 31, rg = tid >> 5;
        const vf4* W24 = (const vf4*)W2;         // W2 [50][128]
        const vf4* sh4 = (const vf4*)sh;
        vf4 bb = ((const vf4*)b2)[cp];
        vf4 acc[4];
        #pragma unroll
        for (int r = 0; r < 4; ++r) acc[r] = bb;
        for (int d4 = 0; d4 < 12; ++d4) {        // d = 0..47
            vf4 w0 = W24[(4 * d4 + 0) * 32 + cp];
            vf4 w1 = W24[(4 * d4 + 1) * 32 + cp];
            vf4 w2 = W24[(4 * d4 + 2) * 32 + cp];
            vf4 w3 = W24[(4 * d4 + 3) * 32 + cp];
            #pragma unroll
            for (int r = 0; r < 4; ++r) {
                vf4 a = sh4[(rg * 4 + r) * 16 + d4];
                acc[r] += a[0] * w0;
                acc[r] += a[1] * w1;
                acc[r] += a[2] * w2;
                acc[r] += a[3] * w3;
            }
        }
        #pragma unroll
        for (int d = 48; d < HD; ++d) {          // tail
            vf4 w = W24[d * 32 + cp];
            #pragma unroll
            for (int r = 0; r < 4; ++r)
                acc[r] += sh[(rg * 4 + r) * 64 + d] * w;
        }
        vf4* fx4 = (vf4*)fx;
        #pragma unroll
        for (int r = 0; r < 4; ++r)
            fx4[(size_t)(row0 + rg * 4 + r) * 32 + cp] = acc[r];
    }
}

// ============================================================================
// k_u: u = fx @ Ws[cat] per category (32 grouped rows/tile) + fused logT.
// ============================================================================
__global__ __launch_bounds__(256) void k_u(const float* __restrict__ fx,
                                           const float* __restrict__ Ws,
                                           const float* __restrict__ fz,
                                           const int* __restrict__ grouped,
                                           const int* __restrict__ offsets,
                                           const int* __restrict__ counts,
                                           float* __restrict__ u,
                                           float* __restrict__ logT) {
    __shared__ float sfx[32 * ZD];               // 16 KB
    __shared__ int srow[32];
    int tid = threadIdx.x;
    int cat = blockIdx.x >> 3;                   // 8 tile-slots per category
    int t0  = blockIdx.x & 7;
    int off = offsets[cat], cnt = counts[cat];
    const vf4* fx4g = (const vf4*)fx;
    const vf4* fz4g = (const vf4*)fz;
    const vf4* Wc4  = (const vf4*)(Ws + (size_t)cat * ZD * ZD);
    vf4* s4 = (vf4*)sfx;
    vf4* u4 = (vf4*)u;

    for (int t = t0; t * 32 < cnt; t += 8) {
        int r0 = t * 32;
        int m  = min(32, cnt - r0);
        __syncthreads();
        if (tid < 32) srow[tid] = (tid < m) ? grouped[off + r0 + tid] : -1;
        __syncthreads();
        #pragma unroll
        for (int f = 0; f < 4; ++f) {
            int idx = tid + f * 256;
            int row = idx >> 5, q = idx & 31;
            int n = srow[row];
            vf4 v = {0.f, 0.f, 0.f, 0.f};
            if (n >= 0) v = fx4g[(size_t)n * 32 + q];
            s4[idx] = v;
        }
        __syncthreads();

        int cp = tid & 31, rg = tid >> 5;
        vf4 acc[4];
        #pragma unroll
        for (int r = 0; r < 4; ++r) acc[r] = (vf4){0.f, 0.f, 0.f, 0.f};
        for (int d4 = 0; d4 < 32; ++d4) {
            vf4 w0 = Wc4[(4 * d4 + 0) * 32 + cp];
            vf4 w1 = Wc4[(4 * d4 + 1) * 32 + cp];
            vf4 w2 = Wc4[(4 * d4 + 2) * 32 + cp];
            vf4 w3 = Wc4[(4 * d4 + 3) * 32 + cp];
            #pragma unroll
            for (int r = 0; r < 4; ++r) {
                vf4 a = s4[(rg * 4 + r) * 32 + d4];
                acc[r] += a[0] * w0;
                acc[r] += a[1] * w1;
                acc[r] += a[2] * w2;
                acc[r] += a[3] * w3;
            }
        }
        #pragma unroll
        for (int r = 0; r < 4; ++r) {
            int n = srow[rg * 4 + r];
            float p = 0.f;
            if (n >= 0) {
                u4[(size_t)n * 32 + cp] = acc[r];
                vf4 fv = fz4g[(size_t)n * 32 + cp];
                p = acc[r][0] * fv[0] + acc[r][1] * fv[1]
                  + acc[r][2] * fv[2] + acc[r][3] * fv[3];
            }
            #pragma unroll
            for (int s = 16; s >= 1; s >>= 1) p += __shfl_xor(p, s, 64);
            if (cp == 0 && n >= 0) logT[n] = logf(softplus_f(p) + EPSF);
        }
    }
}

// ============================================================================
// k_neg: neg_T + final output. 8 i-rows/block, stream group's fz rows.
// ============================================================================
__global__ __launch_bounds__(256) void k_neg(const int* __restrict__ grouped,
                                             const int* __restrict__ offsets,
                                             const int* __restrict__ counts,
                                             const float* __restrict__ u,
                                             const float* __restrict__ fz,
                                             const float* __restrict__ logT,
                                             float* __restrict__ out) {
    __shared__ float su[8 * ZD];                 // 4 KB
    __shared__ int srow[8];
    __shared__ float sred[4][8];
    int tid = threadIdx.x;
    int cat = blockIdx.x >> 4;                   // 16 tile-slots per category
    int t0  = blockIdx.x & 15;
    int off = offsets[cat], cnt = counts[cat];
    const vf4* u4g = (const vf4*)u;

    for (int t = t0; t * 8 < cnt; t += 16) {
        int r0 = t * 8;
        int mI = min(8, cnt - r0);
        __syncthreads();
        if (tid < 8) srow[tid] = (tid < mI) ? grouped[off + r0 + tid] : -1;
        __syncthreads();
        {
            int row = tid >> 5, q = tid & 31;
            int n = srow[row];
            vf4 v = {0.f, 0.f, 0.f, 0.f};
            if (n >= 0) v = u4g[(size_t)n * 32 + q];
            ((vf4*)su)[tid] = v;
        }
        __syncthreads();

        const vf4* su4 = (const vf4*)su;
        float acc[8];
        #pragma unroll
        for (int r = 0; r < 8; ++r) acc[r] = 0.f;
        for (int jj = tid; jj < cnt; jj += 256) {
            int j = grouped[off + jj];
            const vf4* f4 = (const vf4*)(fz + (size_t)j * ZD);
            float dot[8];
            #pragma unroll
            for (int r = 0; r < 8; ++r) dot[r] = 0.f;
            #pragma unroll 4
            for (int q = 0; q < 32; ++q) {
                vf4 bq = f4[q];
                #pragma unroll
                for (int r = 0; r < 8; ++r) {
                    vf4 a = su4[r * 32 + q];
                    dot[r] += a[0] * bq[0] + a[1] * bq[1] + a[2] * bq[2] + a[3] * bq[3];
                }
            }
            #pragma unroll
            for (int r = 0; r < 8; ++r) acc[r] += softplus_f(dot[r]);
        }
        #pragma unroll
        for (int r = 0; r < 8; ++r) {
            float v = acc[r];
            #pragma unroll
            for (int s = 32; s >= 1; s >>= 1) v += __shfl_down(v, s, 64);
            acc[r] = v;
        }
        int lane = tid & 63, w = tid >> 6;
        if (lane == 0) {
            #pragma unroll
            for (int r = 0; r < 8; ++r) sred[w][r] = acc[r];
        }
        __syncthreads();
        if (tid < 8) {
            int n = srow[tid];
            if (n >= 0) {
                float s = sred[0][tid] + sred[1][tid] + sred[2][tid] + sred[3][tid];
                out[n] = logT[n] - logf(s / (float)cnt + EPSF);
            }
        }
    }
}

extern "C" void kernel_launch(void* const* d_in, const int* in_sizes, int n_in,
                              void* d_out, int out_size, void* d_ws, size_t ws_size,
                              hipStream_t stream) {
    const float* x  = (const float*)d_in[0];
    const int*   c  = (const int*)  d_in[1];
    const float* z  = (const float*)d_in[2];
    const float* W1 = (const float*)d_in[3];
    const float* b1 = (const float*)d_in[4];
    const float* W2 = (const float*)d_in[5];
    const float* b2 = (const float*)d_in[6];
    const float* Wz = (const float*)d_in[7];
    const float* bz = (const float*)d_in[8];
    const float* Ws = (const float*)d_in[9];
    float* out = (float*)d_out;

    float* ws   = (float*)d_ws;
    float* W1t  = ws;                            // 64*512
    float* fx   = W1t + 64 * IN_;                // N*128
    float* fz   = fx  + (size_t)N_ * ZD;         // N*128
    float* u    = fz  + (size_t)N_ * ZD;         // N*128
    float* logT = u   + (size_t)N_ * ZD;         // N
    int* counts  = (int*)(logT + N_);            // 64
    int* offsets = counts + CC;                  // 64
    int* grouped = offsets + CC;                 // N

    k_pre <<<CC + 128 + N_ / 32, 256, 0, stream>>>(c, W1, z, Wz, bz, W1t, fz,
                                                   counts, offsets, grouped);
    k_hfx <<<N_ / 32, 256, 0, stream>>>(x, W1t, b1, W2, b2, fx);
    k_u   <<<CC * 8, 256, 0, stream>>>(fx, Ws, fz, grouped, offsets, counts, u, logT);
    k_neg <<<CC * 16, 256, 0, stream>>>(grouped, offsets, counts, u, fz, logT, out);
}

// Round 4
// 222.518 us; speedup vs baseline: 2.3977x; 2.3977x over previous
//
#include <hip/hip_runtime.h>
#include <math.h>

#define N_   8192
#define IN_  512
#define ZD   128
#define CC   64
#define HD   50
#define EPSF 1e-8f

typedef float vf4 __attribute__((ext_vector_type(4)));

__device__ __forceinline__ float softplus_f(float t) {
    return fmaxf(t, 0.f) + log1pf(expf(-fabsf(t)));   // stable softplus
}

// ============================================================================
// k_pre: fused preprocessing.
//   blocks 0..63    : per-category grouping (LDS histogram -> own index list)
//   blocks 64..191  : W1 transpose (pad cols 50->64 with zeros)
//   blocks 192..447 : fz = z @ Wz + bz   (register-tiled 4x4)
// NOTE: all weight-streaming loops carry "#pragma unroll 1" — full unroll of
// these bodies (16 live w-VGPRs each) spilled to scratch in round 3
// (VGPR=256, 346 MB HBM traffic on k_u).
// ============================================================================
__global__ __launch_bounds__(256) void k_pre(const int* __restrict__ c,
                                             const float* __restrict__ W1,
                                             const float* __restrict__ z,
                                             const float* __restrict__ Wz,
                                             const float* __restrict__ bz,
                                             float* __restrict__ W1t,
                                             float* __restrict__ fz,
                                             int* __restrict__ counts,
                                             int* __restrict__ offsets,
                                             int* __restrict__ grouped) {
    int tid = threadIdx.x;
    int b   = blockIdx.x;
    if (b < CC) {
        __shared__ int hist[CC];
        __shared__ int cursor;
        __shared__ int off_s;
        if (tid < CC) hist[tid] = 0;
        if (tid == 0) cursor = 0;
        __syncthreads();
        for (int i = tid; i < N_; i += 256) atomicAdd(&hist[c[i]], 1);
        __syncthreads();
        if (tid == 0) {
            int off = 0;
            for (int q = 0; q < b; ++q) off += hist[q];
            off_s = off;
            counts[b]  = hist[b];
            offsets[b] = off;
        }
        __syncthreads();
        int off = off_s;
        for (int i = tid; i < N_; i += 256) {
            if (c[i] == b) {
                int p = atomicAdd(&cursor, 1);
                grouped[off + p] = i;
            }
        }
    } else if (b < 192) {
        int idx = (b - 64) * 256 + tid;          // 64*512 = 32768
        int k = idx >> 9, d = idx & 511;
        W1t[idx] = (k < HD) ? W1[d * HD + k] : 0.f;
    } else {
        __shared__ float sz[32 * ZD];            // 16 KB
        int row0 = (b - 192) * 32;
        vf4* s4 = (vf4*)sz;
        const vf4* z4 = (const vf4*)(z + (size_t)row0 * ZD);
        #pragma unroll
        for (int f = 0; f < 4; ++f) s4[tid + f * 256] = z4[tid + f * 256];
        __syncthreads();
        int cp = tid & 31, rg = tid >> 5;        // cols 4cp.., rows rg*4..
        const vf4* Wz4 = (const vf4*)Wz;
        vf4 bb = ((const vf4*)bz)[cp];
        vf4 acc[4];
        #pragma unroll
        for (int r = 0; r < 4; ++r) acc[r] = bb;
        #pragma unroll 1
        for (int d4 = 0; d4 < 32; ++d4) {
            vf4 w0 = Wz4[(4 * d4 + 0) * 32 + cp];
            vf4 w1 = Wz4[(4 * d4 + 1) * 32 + cp];
            vf4 w2 = Wz4[(4 * d4 + 2) * 32 + cp];
            vf4 w3 = Wz4[(4 * d4 + 3) * 32 + cp];
            #pragma unroll
            for (int r = 0; r < 4; ++r) {
                vf4 a = s4[(rg * 4 + r) * 32 + d4];
                acc[r] += a[0] * w0;
                acc[r] += a[1] * w1;
                acc[r] += a[2] * w2;
                acc[r] += a[3] * w3;
            }
        }
        vf4* fz4 = (vf4*)fz;
        #pragma unroll
        for (int r = 0; r < 4; ++r)
            fz4[(size_t)(row0 + rg * 4 + r) * 32 + cp] = acc[r];
    }
}

// ============================================================================
// k_hfx: h = relu(x@W1+b1) into LDS, then fx = h@W2+b2 from LDS.
// ============================================================================
__global__ __launch_bounds__(256) void k_hfx(const float* __restrict__ x,
                                             const float* __restrict__ W1t,
                                             const float* __restrict__ b1,
                                             const float* __restrict__ W2,
                                             const float* __restrict__ b2,
                                             float* __restrict__ fx) {
    __shared__ float sx[32 * IN_];               // 64 KB
    __shared__ float sh[32 * 64];                // 8 KB
    int tid  = threadIdx.x;
    int row0 = blockIdx.x * 32;
    vf4* sx4 = (vf4*)sx;
    const vf4* x4 = (const vf4*)(x + (size_t)row0 * IN_);
    #pragma unroll
    for (int f = 0; f < 16; ++f) sx4[tid + f * 256] = x4[tid + f * 256];
    __syncthreads();

    // ---- phase 1: h-tile (32 x 64). thread = 2 rows x 4 cols ----
    {
        int cp = tid & 15, rg = tid >> 4;        // cols 4cp.., rows rg*2..
        const vf4* W1t4 = (const vf4*)W1t;
        vf4 acc0 = {0.f, 0.f, 0.f, 0.f}, acc1 = {0.f, 0.f, 0.f, 0.f};
        #pragma unroll 1
        for (int d4 = 0; d4 < 128; ++d4) {
            vf4 a0 = sx4[(rg * 2 + 0) * 128 + d4];
            vf4 a1 = sx4[(rg * 2 + 1) * 128 + d4];
            #pragma unroll
            for (int i = 0; i < 4; ++i) {
                vf4 w = W1t4[(4 * cp + i) * 128 + d4];
                acc0[i] += a0[0] * w[0] + a0[1] * w[1] + a0[2] * w[2] + a0[3] * w[3];
                acc1[i] += a1[0] * w[0] + a1[1] * w[1] + a1[2] * w[2] + a1[3] * w[3];
            }
        }
        vf4 bb;
        #pragma unroll
        for (int i = 0; i < 4; ++i) {
            int k = 4 * cp + i;
            bb[i] = (k < HD) ? b1[k] : 0.f;
        }
        vf4* sh4 = (vf4*)sh;
        vf4 h0, h1;
        #pragma unroll
        for (int i = 0; i < 4; ++i) {
            h0[i] = fmaxf(acc0[i] + bb[i], 0.f);
            h1[i] = fmaxf(acc1[i] + bb[i], 0.f);
        }
        sh4[(rg * 2 + 0) * 16 + cp] = h0;
        sh4[(rg * 2 + 1) * 16 + cp] = h1;
    }
    __syncthreads();

    // ---- phase 2: fx-tile (32 x 128). thread = 4 rows x 4 cols ----
    {
        int cp = tid & 31, rg = tid >> 5;
        const vf4* W24 = (const vf4*)W2;         // W2 [50][128]
        const vf4* sh4 = (const vf4*)sh;
        vf4 bb = ((const vf4*)b2)[cp];
        vf4 acc[4];
        #pragma unroll
        for (int r = 0; r < 4; ++r) acc[r] = bb;
        #pragma unroll 1
        for (int d4 = 0; d4 < 12; ++d4) {        // d = 0..47
            vf4 w0 = W24[(4 * d4 + 0) * 32 + cp];
            vf4 w1 = W24[(4 * d4 + 1) * 32 + cp];
            vf4 w2 = W24[(4 * d4 + 2) * 32 + cp];
            vf4 w3 = W24[(4 * d4 + 3) * 32 + cp];
            #pragma unroll
            for (int r = 0; r < 4; ++r) {
                vf4 a = sh4[(rg * 4 + r) * 16 + d4];
                acc[r] += a[0] * w0;
                acc[r] += a[1] * w1;
                acc[r] += a[2] * w2;
                acc[r] += a[3] * w3;
            }
        }
        #pragma unroll 1
        for (int d = 48; d < HD; ++d) {          // tail
            vf4 w = W24[d * 32 + cp];
            #pragma unroll
            for (int r = 0; r < 4; ++r)
                acc[r] += sh[(rg * 4 + r) * 64 + d] * w;
        }
        vf4* fx4 = (vf4*)fx;
        #pragma unroll
        for (int r = 0; r < 4; ++r)
            fx4[(size_t)(row0 + rg * 4 + r) * 32 + cp] = acc[r];
    }
}

// ============================================================================
// k_u: u = fx @ Ws[cat] (32 grouped rows/block, early-exit grid) + fused logT.
// ============================================================================
#define MAXT_U 16
__global__ __launch_bounds__(256) void k_u(const float* __restrict__ fx,
                                           const float* __restrict__ Ws,
                                           const float* __restrict__ fz,
                                           const int* __restrict__ grouped,
                                           const int* __restrict__ offsets,
                                           const int* __restrict__ counts,
                                           float* __restrict__ u,
                                           float* __restrict__ logT) {
    __shared__ float sfx[32 * ZD];               // 16 KB
    __shared__ int srow[32];
    int tid = threadIdx.x;
    int cat = blockIdx.x >> 4;
    int t   = blockIdx.x & (MAXT_U - 1);
    int off = offsets[cat], cnt = counts[cat];
    int r0 = t * 32;
    if (r0 >= cnt) return;
    int m = min(32, cnt - r0);
    if (tid < 32) srow[tid] = (tid < m) ? grouped[off + r0 + tid] : -1;
    __syncthreads();

    const vf4* fx4g = (const vf4*)fx;
    const vf4* fz4g = (const vf4*)fz;
    const vf4* Wc4  = (const vf4*)(Ws + (size_t)cat * ZD * ZD);
    vf4* s4 = (vf4*)sfx;
    #pragma unroll
    for (int f = 0; f < 4; ++f) {
        int idx = tid + f * 256;
        int row = idx >> 5, q = idx & 31;
        int n = srow[row];
        vf4 v = {0.f, 0.f, 0.f, 0.f};
        if (n >= 0) v = fx4g[(size_t)n * 32 + q];
        s4[idx] = v;
    }
    __syncthreads();

    int cp = tid & 31, rg = tid >> 5;
    vf4 acc[4];
    #pragma unroll
    for (int r = 0; r < 4; ++r) acc[r] = (vf4){0.f, 0.f, 0.f, 0.f};
    #pragma unroll 1
    for (int d4 = 0; d4 < 32; ++d4) {
        vf4 w0 = Wc4[(4 * d4 + 0) * 32 + cp];
        vf4 w1 = Wc4[(4 * d4 + 1) * 32 + cp];
        vf4 w2 = Wc4[(4 * d4 + 2) * 32 + cp];
        vf4 w3 = Wc4[(4 * d4 + 3) * 32 + cp];
        #pragma unroll
        for (int r = 0; r < 4; ++r) {
            vf4 a = s4[(rg * 4 + r) * 32 + d4];
            acc[r] += a[0] * w0;
            acc[r] += a[1] * w1;
            acc[r] += a[2] * w2;
            acc[r] += a[3] * w3;
        }
    }
    vf4* u4 = (vf4*)u;
    #pragma unroll
    for (int r = 0; r < 4; ++r) {
        int n = srow[rg * 4 + r];
        float p = 0.f;
        if (n >= 0) {
            u4[(size_t)n * 32 + cp] = acc[r];
            vf4 fv = fz4g[(size_t)n * 32 + cp];
            p = acc[r][0] * fv[0] + acc[r][1] * fv[1]
              + acc[r][2] * fv[2] + acc[r][3] * fv[3];
        }
        #pragma unroll
        for (int s = 16; s >= 1; s >>= 1) p += __shfl_xor(p, s, 64);
        if (cp == 0 && n >= 0) logT[n] = logf(softplus_f(p) + EPSF);
    }
}

// ============================================================================
// k_neg: neg_T + final output. 8 i-rows/block, early-exit grid.
// ============================================================================
#define MAXT_N 32
__global__ __launch_bounds__(256) void k_neg(const int* __restrict__ grouped,
                                             const int* __restrict__ offsets,
                                             const int* __restrict__ counts,
                                             const float* __restrict__ u,
                                             const float* __restrict__ fz,
                                             const float* __restrict__ logT,
                                             float* __restrict__ out) {
    __shared__ float su[8 * ZD];                 // 4 KB
    __shared__ int srow[8];
    __shared__ float sred[4][8];
    int tid = threadIdx.x;
    int cat = blockIdx.x >> 5;
    int t   = blockIdx.x & (MAXT_N - 1);
    int off = offsets[cat], cnt = counts[cat];
    int r0 = t * 8;
    if (r0 >= cnt) return;
    int mI = min(8, cnt - r0);
    if (tid < 8) srow[tid] = (tid < mI) ? grouped[off + r0 + tid] : -1;
    __syncthreads();
    {
        int row = tid >> 5, q = tid & 31;
        int n = srow[row];
        vf4 v = {0.f, 0.f, 0.f, 0.f};
        if (n >= 0) v = ((const vf4*)u)[(size_t)n * 32 + q];
        ((vf4*)su)[tid] = v;
    }
    __syncthreads();

    const vf4* su4 = (const vf4*)su;
    float acc[8];
    #pragma unroll
    for (int r = 0; r < 8; ++r) acc[r] = 0.f;
    #pragma unroll 1
    for (int jj = tid; jj < cnt; jj += 256) {
        int j = grouped[off + jj];
        const vf4* f4 = (const vf4*)(fz + (size_t)j * ZD);
        float dot[8];
        #pragma unroll
        for (int r = 0; r < 8; ++r) dot[r] = 0.f;
        #pragma unroll 4
        for (int q = 0; q < 32; ++q) {
            vf4 bq = f4[q];
            #pragma unroll
            for (int r = 0; r < 8; ++r) {
                vf4 a = su4[r * 32 + q];
                dot[r] += a[0] * bq[0] + a[1] * bq[1] + a[2] * bq[2] + a[3] * bq[3];
            }
        }
        #pragma unroll
        for (int r = 0; r < 8; ++r) acc[r] += softplus_f(dot[r]);
    }
    #pragma unroll
    for (int r = 0; r < 8; ++r) {
        float v = acc[r];
        #pragma unroll
        for (int s = 32; s >= 1; s >>= 1) v += __shfl_down(v, s, 64);
        acc[r] = v;
    }
    int lane = tid & 63, w = tid >> 6;
    if (lane == 0) {
        #pragma unroll
        for (int r = 0; r < 8; ++r) sred[w][r] = acc[r];
    }
    __syncthreads();
    if (tid < 8) {
        int n = srow[tid];
        if (n >= 0) {
            float s = sred[0][tid] + sred[1][tid] + sred[2][tid] + sred[3][tid];
            out[n] = logT[n] - logf(s / (float)cnt + EPSF);
        }
    }
}

extern "C" void kernel_launch(void* const* d_in, const int* in_sizes, int n_in,
                              void* d_out, int out_size, void* d_ws, size_t ws_size,
                              hipStream_t stream) {
    const float* x  = (const float*)d_in[0];
    const int*   c  = (const int*)  d_in[1];
    const float* z  = (const float*)d_in[2];
    const float* W1 = (const float*)d_in[3];
    const float* b1 = (const float*)d_in[4];
    const float* W2 = (const float*)d_in[5];
    const float* b2 = (const float*)d_in[6];
    const float* Wz = (const float*)d_in[7];
    const float* bz = (const float*)d_in[8];
    const float* Ws = (const float*)d_in[9];
    float* out = (float*)d_out;

    float* ws   = (float*)d_ws;
    float* W1t  = ws;                            // 64*512
    float* fx   = W1t + 64 * IN_;                // N*128
    float* fz   = fx  + (size_t)N_ * ZD;         // N*128
    float* u    = fz  + (size_t)N_ * ZD;         // N*128
    float* logT = u   + (size_t)N_ * ZD;         // N
    int* counts  = (int*)(logT + N_);            // 64
    int* offsets = counts + CC;                  // 64
    int* grouped = offsets + CC;                 // N

    k_pre <<<CC + 128 + N_ / 32, 256, 0, stream>>>(c, W1, z, Wz, bz, W1t, fz,
                                                   counts, offsets, grouped);
    k_hfx <<<N_ / 32, 256, 0, stream>>>(x, W1t, b1, W2, b2, fx);
    k_u   <<<CC * MAXT_U, 256, 0, stream>>>(fx, Ws, fz, grouped, offsets, counts, u, logT);
    k_neg <<<CC * MAXT_N, 256, 0, stream>>>(grouped, offsets, counts, u, fz, logT, out);
}

// Round 5
// 200.735 us; speedup vs baseline: 2.6579x; 1.1085x over previous
//
#include <hip/hip_runtime.h>
#include <math.h>

#define N_   8192
#define IN_  512
#define ZD   128
#define CC   64
#define HD   50
#define EPSF 1e-8f

typedef float vf4 __attribute__((ext_vector_type(4)));

__device__ __forceinline__ float softplus_f(float t) {
    return fmaxf(t, 0.f) + log1pf(expf(-fabsf(t)));   // stable softplus
}

// ============================================================================
// k_pre: fused preprocessing.
//   blocks 0..63    : per-category grouping (LDS histogram -> own index list)
//   blocks 64..191  : W1 transpose, coalesced reads (pad cols 50->64 zeros)
//   blocks 192..447 : fz = z @ Wz + bz   (register-tiled 4x4)
// "#pragma unroll 1" on weight loops: full unroll spilled in round 3.
// ============================================================================
__global__ __launch_bounds__(256) void k_pre(const int* __restrict__ c,
                                             const float* __restrict__ W1,
                                             const float* __restrict__ z,
                                             const float* __restrict__ Wz,
                                             const float* __restrict__ bz,
                                             float* __restrict__ W1t,
                                             float* __restrict__ fz,
                                             int* __restrict__ counts,
                                             int* __restrict__ offsets,
                                             int* __restrict__ grouped) {
    int tid = threadIdx.x;
    int b   = blockIdx.x;
    if (b < CC) {
        __shared__ int hist[CC];
        __shared__ int cursor;
        __shared__ int off_s;
        if (tid < CC) hist[tid] = 0;
        if (tid == 0) cursor = 0;
        __syncthreads();
        for (int i = tid; i < N_; i += 256) atomicAdd(&hist[c[i]], 1);
        __syncthreads();
        if (tid == 0) {
            int off = 0;
            for (int q = 0; q < b; ++q) off += hist[q];
            off_s = off;
            counts[b]  = hist[b];
            offsets[b] = off;
        }
        __syncthreads();
        int off = off_s;
        for (int i = tid; i < N_; i += 256) {
            if (c[i] == b) {
                int p = atomicAdd(&cursor, 1);
                grouped[off + p] = i;
            }
        }
    } else if (b < 192) {
        // coalesced read of W1[d][0..49], scattered write to W1t[k][d]
        int idx = (b - 64) * 256 + tid;          // 64*512 = 32768
        int d = idx >> 6, k = idx & 63;
        float v = (k < HD) ? W1[d * HD + k] : 0.f;
        W1t[k * IN_ + d] = v;
    } else {
        __shared__ float sz[32 * ZD];            // 16 KB
        int row0 = (b - 192) * 32;
        vf4* s4 = (vf4*)sz;
        const vf4* z4 = (const vf4*)(z + (size_t)row0 * ZD);
        #pragma unroll
        for (int f = 0; f < 4; ++f) s4[tid + f * 256] = z4[tid + f * 256];
        __syncthreads();
        int cp = tid & 31, rg = tid >> 5;        // cols 4cp.., rows rg*4..
        const vf4* Wz4 = (const vf4*)Wz;
        vf4 bb = ((const vf4*)bz)[cp];
        vf4 acc[4];
        #pragma unroll
        for (int r = 0; r < 4; ++r) acc[r] = bb;
        #pragma unroll 1
        for (int d4 = 0; d4 < 32; ++d4) {
            vf4 w0 = Wz4[(4 * d4 + 0) * 32 + cp];
            vf4 w1 = Wz4[(4 * d4 + 1) * 32 + cp];
            vf4 w2 = Wz4[(4 * d4 + 2) * 32 + cp];
            vf4 w3 = Wz4[(4 * d4 + 3) * 32 + cp];
            #pragma unroll
            for (int r = 0; r < 4; ++r) {
                vf4 a = s4[(rg * 4 + r) * 32 + d4];
                acc[r] += a[0] * w0;
                acc[r] += a[1] * w1;
                acc[r] += a[2] * w2;
                acc[r] += a[3] * w3;
            }
        }
        vf4* fz4 = (vf4*)fz;
        #pragma unroll
        for (int r = 0; r < 4; ++r)
            fz4[(size_t)(row0 + rg * 4 + r) * 32 + cp] = acc[r];
    }
}

// ============================================================================
// k_hfx v2: LDS-tiled h = relu(x@W1+b1) (both operands staged, BK=64,
// padded stride 17 vf4), then fx = h@W2+b2 from LDS.
// Thread tile (phase A): 2 rows x 4 strided k-cols (k = cp+16i) so the 16
// distinct w-addresses per wave land on distinct bank groups (2-way max).
// ============================================================================
#define PAD 17   // vf4 row stride in LDS (68 floats) -> bank rotate 4/row
__global__ __launch_bounds__(256) void k_hfx(const float* __restrict__ x,
                                             const float* __restrict__ W1t,
                                             const float* __restrict__ b1,
                                             const float* __restrict__ W2,
                                             const float* __restrict__ b2,
                                             float* __restrict__ fx) {
    __shared__ float sx[32 * 4 * PAD];           // 8.7 KB  (32 rows x 16 vf4)
    __shared__ float sw[64 * 4 * PAD];           // 17.4 KB (64 k    x 16 vf4)
    __shared__ float sh[32 * 4 * PAD];           // 8.7 KB  h-tile 32 x 68
    int tid  = threadIdx.x;
    int row0 = blockIdx.x * 32;
    vf4* sx4 = (vf4*)sx;
    vf4* sw4 = (vf4*)sw;
    const vf4* x4g  = (const vf4*)x;             // row stride 128 vf4
    const vf4* W1t4 = (const vf4*)W1t;           // row stride 128 vf4

    int cp = tid & 15, rg = tid >> 4;            // rows 2rg,2rg+1; k = cp+16i
    float acc0[4] = {0.f, 0.f, 0.f, 0.f};
    float acc1[4] = {0.f, 0.f, 0.f, 0.f};

    #pragma unroll 1
    for (int kc = 0; kc < 8; ++kc) {             // K-chunks of 64
        __syncthreads();
        // stage x-chunk: 512 vf4, 2/thread, coalesced
        #pragma unroll
        for (int f = 0; f < 2; ++f) {
            int idx = tid + f * 256;
            int row = idx >> 4, q = idx & 15;
            sx4[row * PAD + q] = x4g[(size_t)(row0 + row) * 128 + kc * 16 + q];
        }
        // stage w-chunk: 1024 vf4, 4/thread, coalesced
        #pragma unroll
        for (int f = 0; f < 4; ++f) {
            int idx = tid + f * 256;
            int k = idx >> 4, q = idx & 15;
            sw4[k * PAD + q] = W1t4[(size_t)k * 128 + kc * 16 + q];
        }
        __syncthreads();
        #pragma unroll 2
        for (int d4 = 0; d4 < 16; ++d4) {
            vf4 a0 = sx4[(2 * rg + 0) * PAD + d4];
            vf4 a1 = sx4[(2 * rg + 1) * PAD + d4];
            #pragma unroll
            for (int i = 0; i < 4; ++i) {
                vf4 w = sw4[(cp + 16 * i) * PAD + d4];
                acc0[i] += a0[0] * w[0] + a0[1] * w[1] + a0[2] * w[2] + a0[3] * w[3];
                acc1[i] += a1[0] * w[0] + a1[1] * w[1] + a1[2] * w[2] + a1[3] * w[3];
            }
        }
    }
    __syncthreads();
    // bias + relu -> sh
    #pragma unroll
    for (int i = 0; i < 4; ++i) {
        int k = cp + 16 * i;
        float bb = (k < HD) ? b1[k] : 0.f;
        sh[(2 * rg + 0) * 4 * PAD + k] = fmaxf(acc0[i] + bb, 0.f);
        sh[(2 * rg + 1) * 4 * PAD + k] = fmaxf(acc1[i] + bb, 0.f);
    }
    __syncthreads();

    // ---- phase B: fx = sh @ W2 + b2 (32 x 128), thread = 4 rows x 4 cols ----
    {
        int cp2 = tid & 31, rg2 = tid >> 5;
        const vf4* W24 = (const vf4*)W2;         // W2 [50][128]
        const vf4* sh4 = (const vf4*)sh;
        vf4 bb = ((const vf4*)b2)[cp2];
        vf4 acc[4];
        #pragma unroll
        for (int r = 0; r < 4; ++r) acc[r] = bb;
        #pragma unroll 1
        for (int d4 = 0; d4 < 12; ++d4) {        // d = 0..47
            vf4 w0 = W24[(4 * d4 + 0) * 32 + cp2];
            vf4 w1 = W24[(4 * d4 + 1) * 32 + cp2];
            vf4 w2 = W24[(4 * d4 + 2) * 32 + cp2];
            vf4 w3 = W24[(4 * d4 + 3) * 32 + cp2];
            #pragma unroll
            for (int r = 0; r < 4; ++r) {
                vf4 a = sh4[(rg2 * 4 + r) * PAD + d4];
                acc[r] += a[0] * w0;
                acc[r] += a[1] * w1;
                acc[r] += a[2] * w2;
                acc[r] += a[3] * w3;
            }
        }
        #pragma unroll 1
        for (int d = 48; d < HD; ++d) {          // tail
            vf4 w = W24[d * 32 + cp2];
            #pragma unroll
            for (int r = 0; r < 4; ++r)
                acc[r] += sh[(rg2 * 4 + r) * 4 * PAD + d] * w;
        }
        vf4* fx4 = (vf4*)fx;
        #pragma unroll
        for (int r = 0; r < 4; ++r)
            fx4[(size_t)(row0 + rg2 * 4 + r) * 32 + cp2] = acc[r];
    }
}

// ============================================================================
// k_u: u = fx @ Ws[cat] (32 grouped rows/block, early-exit grid) + fused logT.
// ============================================================================
#define MAXT_U 8
__global__ __launch_bounds__(256) void k_u(const float* __restrict__ fx,
                                           const float* __restrict__ Ws,
                                           const float* __restrict__ fz,
                                           const int* __restrict__ grouped,
                                           const int* __restrict__ offsets,
                                           const int* __restrict__ counts,
                                           float* __restrict__ u,
                                           float* __restrict__ logT) {
    __shared__ float sfx[32 * ZD];               // 16 KB
    __shared__ int srow[32];
    int tid = threadIdx.x;
    int cat = blockIdx.x >> 3;
    int t   = blockIdx.x & (MAXT_U - 1);
    int off = offsets[cat], cnt = counts[cat];
    int r0 = t * 32;
    if (r0 >= cnt) return;
    int m = min(32, cnt - r0);
    if (tid < 32) srow[tid] = (tid < m) ? grouped[off + r0 + tid] : -1;
    __syncthreads();

    const vf4* fx4g = (const vf4*)fx;
    const vf4* fz4g = (const vf4*)fz;
    const vf4* Wc4  = (const vf4*)(Ws + (size_t)cat * ZD * ZD);
    vf4* s4 = (vf4*)sfx;
    #pragma unroll
    for (int f = 0; f < 4; ++f) {
        int idx = tid + f * 256;
        int row = idx >> 5, q = idx & 31;
        int n = srow[row];
        vf4 v = {0.f, 0.f, 0.f, 0.f};
        if (n >= 0) v = fx4g[(size_t)n * 32 + q];
        s4[idx] = v;
    }
    __syncthreads();

    int cp = tid & 31, rg = tid >> 5;
    vf4 acc[4];
    #pragma unroll
    for (int r = 0; r < 4; ++r) acc[r] = (vf4){0.f, 0.f, 0.f, 0.f};
    #pragma unroll 1
    for (int d4 = 0; d4 < 32; ++d4) {
        vf4 w0 = Wc4[(4 * d4 + 0) * 32 + cp];
        vf4 w1 = Wc4[(4 * d4 + 1) * 32 + cp];
        vf4 w2 = Wc4[(4 * d4 + 2) * 32 + cp];
        vf4 w3 = Wc4[(4 * d4 + 3) * 32 + cp];
        #pragma unroll
        for (int r = 0; r < 4; ++r) {
            vf4 a = s4[(rg * 4 + r) * 32 + d4];
            acc[r] += a[0] * w0;
            acc[r] += a[1] * w1;
            acc[r] += a[2] * w2;
            acc[r] += a[3] * w3;
        }
    }
    vf4* u4 = (vf4*)u;
    #pragma unroll
    for (int r = 0; r < 4; ++r) {
        int n = srow[rg * 4 + r];
        float p = 0.f;
        if (n >= 0) {
            u4[(size_t)n * 32 + cp] = acc[r];
            vf4 fv = fz4g[(size_t)n * 32 + cp];
            p = acc[r][0] * fv[0] + acc[r][1] * fv[1]
              + acc[r][2] * fv[2] + acc[r][3] * fv[3];
        }
        #pragma unroll
        for (int s = 16; s >= 1; s >>= 1) p += __shfl_xor(p, s, 64);
        if (cp == 0 && n >= 0) logT[n] = logf(softplus_f(p) + EPSF);
    }
}

// ============================================================================
// k_neg: neg_T + output. 8 i-rows/block, 2 j-streams/thread (su LDS read
// reused for two fz rows -> 1 FLOP/LDS-byte, halves fz L2 traffic).
// ============================================================================
#define MAXT_N 32
__global__ __launch_bounds__(256) void k_neg(const int* __restrict__ grouped,
                                             const int* __restrict__ offsets,
                                             const int* __restrict__ counts,
                                             const float* __restrict__ u,
                                             const float* __restrict__ fz,
                                             const float* __restrict__ logT,
                                             float* __restrict__ out) {
    __shared__ float su[8 * ZD];                 // 4 KB
    __shared__ int srow[8];
    __shared__ float sred[4][8];
    int tid = threadIdx.x;
    int cat = blockIdx.x >> 5;
    int t   = blockIdx.x & (MAXT_N - 1);
    int off = offsets[cat], cnt = counts[cat];
    int r0 = t * 8;
    if (r0 >= cnt) return;
    int mI = min(8, cnt - r0);
    if (tid < 8) srow[tid] = (tid < mI) ? grouped[off + r0 + tid] : -1;
    __syncthreads();
    {
        int row = tid >> 5, q = tid & 31;
        int n = srow[row];
        vf4 v = {0.f, 0.f, 0.f, 0.f};
        if (n >= 0) v = ((const vf4*)u)[(size_t)n * 32 + q];
        ((vf4*)su)[tid] = v;
    }
    __syncthreads();

    const vf4* su4 = (const vf4*)su;
    const vf4* fz4g = (const vf4*)fz;
    float acc[8];
    #pragma unroll
    for (int r = 0; r < 8; ++r) acc[r] = 0.f;
    #pragma unroll 1
    for (int base = 0; base < cnt; base += 512) {
        int jjA = base + tid, jjB = base + 256 + tid;
        bool vA = jjA < cnt, vB = jjB < cnt;
        int jA = grouped[off + min(jjA, cnt - 1)];
        int jB = grouped[off + min(jjB, cnt - 1)];
        const vf4* fA = fz4g + (size_t)jA * 32;
        const vf4* fB = fz4g + (size_t)jB * 32;
        float dA[8], dB[8];
        #pragma unroll
        for (int r = 0; r < 8; ++r) { dA[r] = 0.f; dB[r] = 0.f; }
        #pragma unroll 4
        for (int q = 0; q < 32; ++q) {
            vf4 bA = fA[q];
            vf4 bB = fB[q];
            #pragma unroll
            for (int r = 0; r < 8; ++r) {
                vf4 a = su4[r * 32 + q];
                dA[r] += a[0] * bA[0] + a[1] * bA[1] + a[2] * bA[2] + a[3] * bA[3];
                dB[r] += a[0] * bB[0] + a[1] * bB[1] + a[2] * bB[2] + a[3] * bB[3];
            }
        }
        #pragma unroll
        for (int r = 0; r < 8; ++r) {
            if (vA) acc[r] += softplus_f(dA[r]);
            if (vB) acc[r] += softplus_f(dB[r]);
        }
    }
    #pragma unroll
    for (int r = 0; r < 8; ++r) {
        float v = acc[r];
        #pragma unroll
        for (int s = 32; s >= 1; s >>= 1) v += __shfl_down(v, s, 64);
        acc[r] = v;
    }
    int lane = tid & 63, w = tid >> 6;
    if (lane == 0) {
        #pragma unroll
        for (int r = 0; r < 8; ++r) sred[w][r] = acc[r];
    }
    __syncthreads();
    if (tid < 8) {
        int n = srow[tid];
        if (n >= 0) {
            float s = sred[0][tid] + sred[1][tid] + sred[2][tid] + sred[3][tid];
            out[n] = logT[n] - logf(s / (float)cnt + EPSF);
        }
    }
}

extern "C" void kernel_launch(void* const* d_in, const int* in_sizes, int n_in,
                              void* d_out, int out_size, void* d_ws, size_t ws_size,
                              hipStream_t stream) {
    const float* x  = (const float*)d_in[0];
    const int*   c  = (const int*)  d_in[1];
    const float* z  = (const float*)d_in[2];
    const float* W1 = (const float*)d_in[3];
    const float* b1 = (const float*)d_in[4];
    const float* W2 = (const float*)d_in[5];
    const float* b2 = (const float*)d_in[6];
    const float* Wz = (const float*)d_in[7];
    const float* bz = (const float*)d_in[8];
    const float* Ws = (const float*)d_in[9];
    float* out = (float*)d_out;

    float* ws   = (float*)d_ws;
    float* W1t  = ws;                            // 64*512
    float* fx   = W1t + 64 * IN_;                // N*128
    float* fz   = fx  + (size_t)N_ * ZD;         // N*128
    float* u    = fz  + (size_t)N_ * ZD;         // N*128
    float* logT = u   + (size_t)N_ * ZD;         // N
    int* counts  = (int*)(logT + N_);            // 64
    int* offsets = counts + CC;                  // 64
    int* grouped = offsets + CC;                 // N

    k_pre <<<CC + 128 + N_ / 32, 256, 0, stream>>>(c, W1, z, Wz, bz, W1t, fz,
                                                   counts, offsets, grouped);
    k_hfx <<<N_ / 32, 256, 0, stream>>>(x, W1t, b1, W2, b2, fx);
    k_u   <<<CC * MAXT_U, 256, 0, stream>>>(fx, Ws, fz, grouped, offsets, counts, u, logT);
    k_neg <<<CC * MAXT_N, 256, 0, stream>>>(grouped, offsets, counts, u, fz, logT, out);
}